// Round 10
// baseline (115.663 us; speedup 1.0000x reference)
//
#include <hip/hip_runtime.h>

// ROI point pooling, 4 stream-ordered kernels. R10: mask BW=2 (12512 waves,
// caps the 32-wave/CU occupancy limit) to hide the s_load->v_cmp->s_and->
// v_cndmask chains that left R8/R9's mask at 37% VALUBusy / 21% occupancy.
//
// prep: bounds[A][8] = xl,xh,yl,yh,h,cx,cy,0 ; zeros sbtot.
// mask (BW=2 words/wave): lane = point. Per anchor j: s_load bounds row, 5
//   single-v_cmp ballots (ballot_w64) combined with s_and_b64, deposit
//   anchor j's words into lane j (cndmask). Stores maskT[wd][a] (coalesced),
//   qtot[g][a], and atomicAdd into sbtot[g/32][a].
// E1 (index compaction): wave = (c,g), lane = anchor. base = sum sbtot[k<sb]
//   (<=24 rows) + sum qtot[sb*32..g) (<=31 rows), coalesced + unrolled.
//   Walk own 2 words, ffs-emit 4B point-INDICES to idx[a][slot<n]. Last
//   block writes counts.
// E2 (gather): wave = (a, 64-slot chunk). Coalesced idx load, divergent pts
//   gather with ALL lanes active, coalesced 768B row stores; slots >= count
//   get zeros (absorbs the output clear; d_out is 0xAA-poisoned).
//
// Slot of point i = #(in-box points with index < i) == reference cumsum.

#if defined(__has_builtin)
#  if __has_builtin(__builtin_amdgcn_ballot_w64)
#    define BALLOT64(x) __builtin_amdgcn_ballot_w64(x)
#  else
#    define BALLOT64(x) __ballot(x)
#  endif
#else
#  define BALLOT64(x) __ballot(x)
#endif

#define BW  2    // words per mask/E1 block (128 points)
#define SBW 32   // qtot rows per sbtot row (4096 points)

__global__ __launch_bounds__(256) void prep_kernel(
    const float* __restrict__ anc, float* __restrict__ bounds,
    int* __restrict__ sbtot, int A, int nsb2)
{
    for (int gt = blockIdx.x * 256 + threadIdx.x; gt < A + nsb2 * A;
         gt += gridDim.x * 256) {
        if (gt < A) {
            const float cx = anc[gt * 6 + 0], cy = anc[gt * 6 + 1];
            const float w  = anc[gt * 6 + 3], l  = anc[gt * 6 + 4], h = anc[gt * 6 + 5];
            float* b = bounds + (size_t)gt * 8;
            b[0] = cx - 0.5f * w; b[1] = cx + 0.5f * w;
            b[2] = cy - 0.5f * l; b[3] = cy + 0.5f * l;
            b[4] = h; b[5] = cx; b[6] = cy; b[7] = 0.0f;
        } else {
            sbtot[gt - A] = 0;
        }
    }
}

__global__ __launch_bounds__(256) void mask_kernel(
    const float* __restrict__ pts, const float* __restrict__ bounds,
    unsigned long long* __restrict__ maskT, int* __restrict__ qtot,
    int* __restrict__ sbtot, int N, int W, int A, int NQB)
{
    const int it = __builtin_amdgcn_readfirstlane(blockIdx.x * 4 + (threadIdx.x >> 6));
    const int lane = threadIdx.x & 63;
    const int NGRP = A >> 6;
    if (it >= NGRP * NQB) return;
    const int c   = it / NQB;          // anchor group (uniform)
    const int g   = it % NQB;          // 2-word block (uniform)
    const int wd0 = g * BW;

    float px[BW], py[BW], pz[BW];
    unsigned long long zv[BW], myw[BW];
    #pragma unroll
    for (int u = 0; u < BW; ++u) {
        const int i  = (wd0 + u) * 64 + lane;
        const int ic = i < N ? i : N - 1;
        px[u] = pts[3 * ic + 0];
        py[u] = pts[3 * ic + 1];
        pz[u] = pts[3 * ic + 2];
        zv[u] = BALLOT64(pz[u] >= 0.0f) & BALLOT64(i < N);
        myw[u] = 0ull;
    }

    const float* bb = bounds + (size_t)c * 64 * 8;
    #pragma unroll 8
    for (int j = 0; j < 64; ++j) {
        const float xl = bb[j * 8 + 0], xh = bb[j * 8 + 1];  // uniform -> s_load
        const float yl = bb[j * 8 + 2], yh = bb[j * 8 + 3];
        const float hh = bb[j * 8 + 4];
        #pragma unroll
        for (int u = 0; u < BW; ++u) {
            const unsigned long long b =
                BALLOT64(px[u] >= xl) & BALLOT64(px[u] <= xh) &
                BALLOT64(py[u] >= yl) & BALLOT64(py[u] <= yh) &
                BALLOT64(pz[u] <= hh) & zv[u];        // s_and_b64 combines
            if (lane == j) myw[u] = b;                // cndmask deposit
        }
    }

    const int a = c * 64 + lane;
    int pcs = 0;
    #pragma unroll
    for (int u = 0; u < BW; ++u) {
        pcs += __popcll(myw[u]);                      // OOB words are all-0
        const int wd = wd0 + u;
        if (wd < W) maskT[(size_t)wd * A + a] = myw[u];  // 512B coalesced
    }
    qtot[g * A + a] = pcs;                            // coalesced
    atomicAdd(&sbtot[(g / SBW) * A + a], pcs);        // hierarchical subtotal
}

__global__ __launch_bounds__(256) void e1_kernel(
    const unsigned long long* __restrict__ maskT, const int* __restrict__ qtot,
    const int* __restrict__ sbtot, int* __restrict__ idx,
    int* __restrict__ cnts, float* __restrict__ out_cnt,
    int n, int A, int W, int NQB)
{
    const int it = __builtin_amdgcn_readfirstlane(blockIdx.x * 4 + (threadIdx.x >> 6));
    const int lane = threadIdx.x & 63;
    const int NGRP = A >> 6;
    if (it >= NGRP * NQB) return;
    const int c  = it / NQB;
    const int g  = it % NQB;
    const int sb = g / SBW;
    const int a  = c * 64 + lane;

    // Hierarchical exclusive prefix: sbtot rows + intra-sb qtot rows,
    // 8-way unrolled so 8 independent coalesced loads share each waitcnt.
    int base = 0;
    {
        int k = 0;
        for (; k + 8 <= sb; k += 8) {
            const int v0 = sbtot[(k + 0) * A + a], v1 = sbtot[(k + 1) * A + a];
            const int v2 = sbtot[(k + 2) * A + a], v3 = sbtot[(k + 3) * A + a];
            const int v4 = sbtot[(k + 4) * A + a], v5 = sbtot[(k + 5) * A + a];
            const int v6 = sbtot[(k + 6) * A + a], v7 = sbtot[(k + 7) * A + a];
            base += ((v0 + v1) + (v2 + v3)) + ((v4 + v5) + (v6 + v7));
        }
        for (; k < sb; ++k) base += sbtot[k * A + a];
        int q = sb * SBW;
        for (; q + 8 <= g; q += 8) {
            const int v0 = qtot[(q + 0) * A + a], v1 = qtot[(q + 1) * A + a];
            const int v2 = qtot[(q + 2) * A + a], v3 = qtot[(q + 3) * A + a];
            const int v4 = qtot[(q + 4) * A + a], v5 = qtot[(q + 5) * A + a];
            const int v6 = qtot[(q + 6) * A + a], v7 = qtot[(q + 7) * A + a];
            base += ((v0 + v1) + (v2 + v3)) + ((v4 + v5) + (v6 + v7));
        }
        for (; q < g; ++q) base += qtot[q * A + a];
    }

    // Walk own words; emit 4B indices (ordered); pos past n just counts.
    int pos = base;
    int* const idxa = idx + (size_t)a * n;
    #pragma unroll
    for (int u = 0; u < BW; ++u) {
        const int wd = g * BW + u;
        if (wd >= W) break;
        unsigned long long w = maskT[(size_t)wd * A + a];   // coalesced
        while (w) {
            const int bix = __ffsll((long long)w) - 1;
            w &= w - 1ull;
            if (pos < n) idxa[pos] = wd * 64 + bix;
            ++pos;
        }
    }

    if (g == NQB - 1) {                 // pos == total unclamped count
        const int cc = pos < n ? pos : n;
        cnts[a] = cc;
        out_cnt[a] = (float)cc;
    }
}

__global__ __launch_bounds__(256) void e2_kernel(
    const float* __restrict__ pts, const float* __restrict__ bounds,
    const int* __restrict__ idx, const int* __restrict__ cnts,
    float* __restrict__ out_pts, int n, int A, int KCH)
{
    const int wv = __builtin_amdgcn_readfirstlane(blockIdx.x * 4 + (threadIdx.x >> 6));
    const int lane = threadIdx.x & 63;
    if (wv >= A * KCH) return;
    const int a = wv / KCH;             // uniform -> s_loads below
    const int k = wv % KCH;

    const int cnt  = cnts[a];           // uniform
    const float cx = bounds[a * 8 + 5], cy = bounds[a * 8 + 6];
    const int slot = k * 64 + lane;
    if (slot >= n) return;

    float vx = 0.f, vy = 0.f, vz = 0.f;
    if (slot < cnt) {
        const int i = idx[(size_t)a * n + slot];   // coalesced 256B
        vx = pts[3 * i + 0] - cx;                  // divergent gather, all lanes
        vy = pts[3 * i + 1] - cy;
        vz = pts[3 * i + 2];
    }
    float* o = out_pts + ((size_t)a * n + slot) * 3;  // 768B/row coalesced
    o[0] = vx; o[1] = vy; o[2] = vz;
}

// ---- Fallback (round-1 kernel) used only if A % 64 != 0 / ws too small ----
__global__ __launch_bounds__(256) void roi_pool_kernel(
    const float* __restrict__ pts, const float* __restrict__ anc,
    float* __restrict__ out_pts, float* __restrict__ out_cnt, int N, int n)
{
    const int a = blockIdx.x;
    const float cx = anc[a * 6 + 0], cy = anc[a * 6 + 1];
    const float w  = anc[a * 6 + 3], l  = anc[a * 6 + 4], h = anc[a * 6 + 5];
    const float xmin = cx - 0.5f * w, xmax = cx + 0.5f * w;
    const float ymin = cy - 0.5f * l, ymax = cy + 0.5f * l;
    const int tid = threadIdx.x, wave = tid >> 6, lane = tid & 63;
    __shared__ int s_tot[4];
    int base = 0;
    float* const outa = out_pts + (size_t)a * n * 3;
    for (int start = 0; start < N; start += 256) {
        const int i = start + tid;
        bool m = false;
        float px = 0.f, py = 0.f, pz = 0.f;
        if (i < N) {
            px = pts[3 * i]; py = pts[3 * i + 1]; pz = pts[3 * i + 2];
            m = (px >= xmin) & (px <= xmax) & (py >= ymin) & (py <= ymax) &
                (pz >= 0.0f) & (pz <= h);
        }
        const unsigned long long ball = __ballot(m);
        const int lanePfx = __popcll(ball & ((1ull << lane) - 1ull));
        if (lane == 0) s_tot[wave] = __popcll(ball);
        __syncthreads();
        const int t0 = s_tot[0], t1 = s_tot[1], t2 = s_tot[2], t3 = s_tot[3];
        int offs = base;
        if (wave > 0) offs += t0;
        if (wave > 1) offs += t1;
        if (wave > 2) offs += t2;
        const int slot = offs + lanePfx;
        if (m && slot < n) {
            float* o = outa + (size_t)slot * 3;
            o[0] = px - cx; o[1] = py - cy; o[2] = pz;
        }
        base += t0 + t1 + t2 + t3;
        __syncthreads();
        if (base >= n) break;
    }
    const int count = base < n ? base : n;
    if (tid == 0) out_cnt[a] = (float)count;
    for (int s = count + tid; s < n; s += 256) {
        float* o = outa + (size_t)s * 3;
        o[0] = 0.f; o[1] = 0.f; o[2] = 0.f;
    }
}

extern "C" void kernel_launch(void* const* d_in, const int* in_sizes, int n_in,
                              void* d_out, int out_size, void* d_ws, size_t ws_size,
                              hipStream_t stream) {
    const float* pts = (const float*)d_in[0];
    const float* anc = (const float*)d_in[1];
    const int N = in_sizes[0] / 3;          // 100000
    const int A = in_sizes[1] / 6;          // 1024
    const int n = (out_size / A - 1) / 3;   // 512

    float* out_pts = (float*)d_out;
    float* out_cnt = (float*)d_out + (size_t)A * n * 3;

    const int W    = (N + 63) / 64;         // words per anchor (1563)
    const int NQB  = (W + BW - 1) / BW;     // 2-word blocks (782)
    const int NSB2 = (NQB + SBW - 1) / SBW; // sbtot rows (25)

    const size_t mask_bytes  = ((size_t)W * A + 64) * 8;
    const size_t qtot_bytes  = (size_t)NQB * A * sizeof(int);
    const size_t sbtot_bytes = (size_t)NSB2 * A * sizeof(int);
    const size_t bound_bytes = (size_t)A * 8 * sizeof(float);
    const size_t cnts_bytes  = (size_t)A * sizeof(int);
    const size_t idx_bytes   = (size_t)A * n * sizeof(int);
    const size_t total_ws = mask_bytes + qtot_bytes + sbtot_bytes +
                            bound_bytes + cnts_bytes + idx_bytes;

    if ((A & 63) || ws_size < total_ws) {
        roi_pool_kernel<<<dim3(A), dim3(256), 0, stream>>>(pts, anc, out_pts, out_cnt, N, n);
        return;
    }

    char* p = (char*)d_ws;
    unsigned long long* maskT = (unsigned long long*)p;  p += mask_bytes;
    int*   qtot   = (int*)p;    p += qtot_bytes;
    int*   sbtot  = (int*)p;    p += sbtot_bytes;
    float* bounds = (float*)p;  p += bound_bytes;
    int*   cnts   = (int*)p;    p += cnts_bytes;
    int*   idx    = (int*)p;

    const int NGRP   = A >> 6;
    const int mwaves = NGRP * NQB;          // 12512
    const int KCH    = (n + 63) / 64;       // 8 slot-chunks per anchor
    const int ewaves = A * KCH;             // 8192

    prep_kernel<<<dim3(104), dim3(256), 0, stream>>>(anc, bounds, sbtot, A, NSB2);
    mask_kernel<<<dim3((mwaves + 3) / 4), dim3(256), 0, stream>>>(
        pts, bounds, maskT, qtot, sbtot, N, W, A, NQB);
    e1_kernel<<<dim3((mwaves + 3) / 4), dim3(256), 0, stream>>>(
        maskT, qtot, sbtot, idx, cnts, out_cnt, n, A, W, NQB);
    e2_kernel<<<dim3((ewaves + 3) / 4), dim3(256), 0, stream>>>(
        pts, bounds, idx, cnts, out_pts, n, A, KCH);
}